// Round 1
// baseline (9325.780 us; speedup 1.0000x reference)
//
#include <hip/hip_runtime.h>
#include <stdint.h>

// LEM recurrent net, MI355X persistent-kernel implementation.
// Partition: NGRP=4 batch groups (64 rows) x CBLK=48 column-blocks (16 state
// cols each) = 192 blocks, 1 block/CU (LDS-bound), weights pinned in LDS.
// Two group-local spin barriers per timestep (agent-scope release/acquire).

#define NINP 128
#define NHID 768
#define NOUT 128
#define T_STEPS 256
#define BATCH 256

#define NGRP 4
#define CBLK 48
#define NBLK (NGRP * CBLK)      // 192 blocks
#define MROWS (BATCH / NGRP)    // 64 rows per group
#define COLS 16                 // state columns per block
#define KH (NHID / 32)          // 24 K-iters for K=768
#define KI (NINP / 32)          // 4  K-iters for K=128

// LDS tile indices (each tile = 16 cols x 32 k bf16 = 1KB, fragment-major)
#define T_HID0 0                // 3 segs * 24  = 72 tiles (W_hid)
#define T_INP0 72               // 4 segs * 4   = 16 tiles (W_inp)
#define T_WZ0  88               // 24 tiles (W_z)
#define NTILES 112              // 112 KB LDS

typedef short bf16x8 __attribute__((ext_vector_type(8)));
typedef float f32x4 __attribute__((ext_vector_type(4)));

__device__ __forceinline__ unsigned short f2b(float f) {
  union { float f; unsigned u; } x; x.f = f;
  return (unsigned short)((x.u + 0x7fffu + ((x.u >> 16) & 1u)) >> 16);  // RNE
}
__device__ __forceinline__ float b2f(unsigned short h) {
  union { unsigned u; float f; } x; x.u = ((unsigned)h) << 16; return x.f;
}
__device__ __forceinline__ float fsig(float x) { return 1.0f / (1.0f + __expf(-x)); }
__device__ __forceinline__ float ftanh(float x) {
  float e = __expf(2.0f * x);          // inf-safe: ->1 / ->-1 at extremes
  return 1.0f - 2.0f / (e + 1.0f);
}

#define MFMA16(a, b, c) __builtin_amdgcn_mfma_f32_16x16x32_bf16(a, b, c, 0, 0, 0)

// Split fp32 into hi/lo bf16 fragments (state operands ~fp32-accurate in MFMA)
__device__ __forceinline__ void split8(const float* p, bf16x8* hi, bf16x8* lo) {
  union { bf16x8 v; unsigned short s[8]; } H, L;
#pragma unroll
  for (int e = 0; e < 8; ++e) {
    float v = p[e];
    unsigned short h = f2b(v);
    H.s[e] = h;
    L.s[e] = f2b(v - b2f(h));
  }
  *hi = H.v; *lo = L.v;
}

// ---- group barrier: monotonically increasing counter, agent scope ----
__device__ __forceinline__ void bar_arrive(unsigned* ctr) {
  __syncthreads();  // all block stores vmcnt-drained before release
  if (threadIdx.x == 0)
    __hip_atomic_fetch_add(ctr, 1u, __ATOMIC_RELEASE, __HIP_MEMORY_SCOPE_AGENT);
}
__device__ __forceinline__ void bar_wait(unsigned* ctr, unsigned target) {
  if (threadIdx.x == 0) {
    while (__hip_atomic_load(ctr, __ATOMIC_RELAXED, __HIP_MEMORY_SCOPE_AGENT) < target)
      __builtin_amdgcn_s_sleep(1);
    __threadfence();  // agent acquire: invalidate L1/L2 so state reads are fresh
  }
  __syncthreads();
}

__global__ __launch_bounds__(256, 1) void lem_kernel(
    const float* __restrict__ x,       // [T][B][NINP]
    const float* __restrict__ W_inp,   // [4*NHID][NINP]
    const float* __restrict__ b_inp,   // [4*NHID]
    const float* __restrict__ W_hid,   // [3*NHID][NHID]
    const float* __restrict__ b_hid,   // [3*NHID]
    const float* __restrict__ W_z,     // [NHID][NHID]
    const float* __restrict__ b_z,     // [NHID]
    const float* __restrict__ W_cls,   // [NOUT][NHID]
    const float* __restrict__ b_cls,   // [NOUT]
    float* __restrict__ out,           // [B][NOUT]
    unsigned short* __restrict__ ybh, unsigned short* __restrict__ ybl,  // y hi/lo [B][NHID]
    unsigned short* __restrict__ zbh, unsigned short* __restrict__ zbl,  // z hi/lo
    unsigned* __restrict__ ctrs)       // NGRP counters, 128B apart
{
  __shared__ unsigned short wlds[NTILES * 512];  // 112 KB

  const int tid = threadIdx.x;
  const int l   = tid & 63;
  const int w   = tid >> 6;            // wave 0..3 -> 16-row tile
  const int g   = blockIdx.x / CBLK;
  const int c   = blockIdx.x % CBLK;
  const int colbase = c * COLS;
  const int lc  = l & 15;              // A row-in-tile / B col-in-tile
  const int kg8 = (l >> 4) * 8;        // k-group offset

  // ---- one-time: load + pack weight slices into LDS (bf16, fragment-major)
  for (int idx = tid; idx < NTILES * 512; idx += 256) {
    int t = idx >> 9;
    int r = idx & 511;
    int ll = r >> 3;
    int e  = r & 7;
    int col16 = ll & 15;
    int kk = ((ll >> 4) * 8) + e;
    float v;
    if (t < T_INP0) {                      // W_hid: t = seg*24 + kt
      int seg = t / 24, kt = t % 24;
      v = W_hid[(size_t)(seg * NHID + colbase + col16) * NHID + kt * 32 + kk];
    } else if (t < T_WZ0) {                // W_inp: t-72 = seg*4 + kt
      int u = t - T_INP0; int seg = u >> 2, kt = u & 3;
      v = W_inp[(size_t)(seg * NHID + colbase + col16) * NINP + kt * 32 + kk];
    } else {                               // W_z: kt = t-88
      int kt = t - T_WZ0;
      v = W_z[(size_t)(colbase + col16) * NHID + kt * 32 + kk];
    }
    wlds[idx] = f2b(v);
  }
  __syncthreads();

#define LDSB(t) (*(const bf16x8*)&wlds[((t) << 9) + (l << 3)])

  // per-lane fixed indices / biases (fp32, exact)
  const int col  = colbase + lc;                // this lane's state column
  const int rowA = g * MROWS + w * 16 + lc;     // A-fragment row (batch)
  const int rowD = g * MROWS + w * 16 + (l >> 4) * 4;  // D rows rowD..rowD+3
  const float c1 = b_inp[col] + b_hid[col];                       // dt1
  const float c2 = b_inp[NHID + col] + b_hid[NHID + col];         // dt2
  const float cy = b_inp[3 * NHID + col] + b_hid[2 * NHID + col]; // y gate
  const float cz = b_inp[2 * NHID + col] + b_z[col];              // i_z + b_z
  unsigned* ctr = ctrs + g * 32;

  // input-projection accumulators for step 0
  f32x4 ai0{0,0,0,0}, ai1{0,0,0,0}, ai2{0,0,0,0}, ai3{0,0,0,0};
  {
    const float* xp0 = x + (size_t)rowA * NINP;
#pragma unroll
    for (int kt = 0; kt < KI; ++kt) {
      bf16x8 ah, al;
      split8(xp0 + kt * 32 + kg8, &ah, &al);
      ai0 = MFMA16(ah, LDSB(T_INP0 + 0 * 4 + kt), ai0);
      ai0 = MFMA16(al, LDSB(T_INP0 + 0 * 4 + kt), ai0);
      ai1 = MFMA16(ah, LDSB(T_INP0 + 1 * 4 + kt), ai1);
      ai1 = MFMA16(al, LDSB(T_INP0 + 1 * 4 + kt), ai1);
      ai2 = MFMA16(ah, LDSB(T_INP0 + 2 * 4 + kt), ai2);
      ai2 = MFMA16(al, LDSB(T_INP0 + 2 * 4 + kt), ai2);
      ai3 = MFMA16(ah, LDSB(T_INP0 + 3 * 4 + kt), ai3);
      ai3 = MFMA16(al, LDSB(T_INP0 + 3 * 4 + kt), ai3);
    }
  }

  f32x4 yloc{0,0,0,0}, zloc{0,0,0,0}, msb{0,0,0,0};
  unsigned target = 0;

  for (int s = 0; s < T_STEPS; ++s) {
    // ---------- phase A: hid = y @ W_hid^T (hi/lo A), z update ----------
    f32x4 h0{0,0,0,0}, h1{0,0,0,0}, h2{0,0,0,0};
    {
      const unsigned short* yh = ybh + (size_t)rowA * NHID + kg8;
      const unsigned short* yl = ybl + (size_t)rowA * NHID + kg8;
#pragma unroll 4
      for (int kt = 0; kt < KH; ++kt) {
        bf16x8 ah = *(const bf16x8*)(yh + kt * 32);
        bf16x8 al = *(const bf16x8*)(yl + kt * 32);
        bf16x8 bb0 = LDSB(0 * KH + kt);
        bf16x8 bb1 = LDSB(1 * KH + kt);
        bf16x8 bb2 = LDSB(2 * KH + kt);
        h0 = MFMA16(ah, bb0, h0); h0 = MFMA16(al, bb0, h0);
        h1 = MFMA16(ah, bb1, h1); h1 = MFMA16(al, bb1, h1);
        h2 = MFMA16(ah, bb2, h2); h2 = MFMA16(al, bb2, h2);
      }
    }
#pragma unroll
    for (int i = 0; i < 4; ++i) {
      float a1 = fsig(ai0[i] + h0[i] + c1);          // ms_dt_bar
      float a2 = fsig(ai1[i] + h1[i] + c2);          // ms_dt
      float gg = ftanh(ai3[i] + h2[i] + cy);
      float zn = (1.0f - a2) * zloc[i] + a2 * gg;
      zloc[i] = zn;
      msb[i] = a1;
      unsigned short zh = f2b(zn);
      size_t o = (size_t)(rowD + i) * NHID + col;
      zbh[o] = zh;
      zbl[o] = f2b(zn - b2f(zh));
    }
    bar_arrive(ctr); target += CBLK;
    unsigned t1 = target;

    // overlap barrier latency: input projection for step s+1
    f32x4 ni0{0,0,0,0}, ni1{0,0,0,0}, ni2{0,0,0,0}, ni3{0,0,0,0};
    if (s + 1 < T_STEPS) {
      const float* xp = x + ((size_t)(s + 1) * BATCH + rowA) * NINP;
#pragma unroll
      for (int kt = 0; kt < KI; ++kt) {
        bf16x8 ah, al;
        split8(xp + kt * 32 + kg8, &ah, &al);
        ni0 = MFMA16(ah, LDSB(T_INP0 + 0 * 4 + kt), ni0);
        ni0 = MFMA16(al, LDSB(T_INP0 + 0 * 4 + kt), ni0);
        ni1 = MFMA16(ah, LDSB(T_INP0 + 1 * 4 + kt), ni1);
        ni1 = MFMA16(al, LDSB(T_INP0 + 1 * 4 + kt), ni1);
        ni2 = MFMA16(ah, LDSB(T_INP0 + 2 * 4 + kt), ni2);
        ni2 = MFMA16(al, LDSB(T_INP0 + 2 * 4 + kt), ni2);
        ni3 = MFMA16(ah, LDSB(T_INP0 + 3 * 4 + kt), ni3);
        ni3 = MFMA16(al, LDSB(T_INP0 + 3 * 4 + kt), ni3);
      }
    }
    bar_wait(ctr, t1);

    // ---------- phase B: zWz = z @ W_z^T, y update ----------
    f32x4 az0{0,0,0,0}, az1{0,0,0,0};
    {
      const unsigned short* zh = zbh + (size_t)rowA * NHID + kg8;
      const unsigned short* zl = zbl + (size_t)rowA * NHID + kg8;
#pragma unroll 4
      for (int kt = 0; kt < KH; kt += 2) {
        bf16x8 ah0 = *(const bf16x8*)(zh + kt * 32);
        bf16x8 al0 = *(const bf16x8*)(zl + kt * 32);
        bf16x8 bb0 = LDSB(T_WZ0 + kt);
        az0 = MFMA16(ah0, bb0, az0); az0 = MFMA16(al0, bb0, az0);
        bf16x8 ah1 = *(const bf16x8*)(zh + (kt + 1) * 32);
        bf16x8 al1 = *(const bf16x8*)(zl + (kt + 1) * 32);
        bf16x8 bb1 = LDSB(T_WZ0 + kt + 1);
        az1 = MFMA16(ah1, bb1, az1); az1 = MFMA16(al1, bb1, az1);
      }
    }
#pragma unroll
    for (int i = 0; i < 4; ++i) {
      float tt = ftanh(az0[i] + az1[i] + ai2[i] + cz);
      float yn = (1.0f - msb[i]) * yloc[i] + msb[i] * tt;
      yloc[i] = yn;
      unsigned short yh = f2b(yn);
      size_t o = (size_t)(rowD + i) * NHID + col;
      ybh[o] = yh;
      ybl[o] = f2b(yn - b2f(yh));
    }
    bar_arrive(ctr); target += CBLK;
    bar_wait(ctr, target);

    ai0 = ni0; ai1 = ni1; ai2 = ni2; ai3 = ni3;
  }

  // ---------- epilogue: out = y @ W_cls^T + b_cls (blocks c<8) ----------
  if (c < 8) {
    f32x4 ao0{0,0,0,0}, ao1{0,0,0,0};
    const unsigned short* yh = ybh + (size_t)rowA * NHID + kg8;
    const unsigned short* yl = ybl + (size_t)rowA * NHID + kg8;
    for (int kt = 0; kt < KH; kt += 2) {
      {
        const float* wp = W_cls + (size_t)(colbase + lc) * NHID + kt * 32 + kg8;
        bf16x8 bh, bl;
        split8(wp, &bh, &bl);
        bf16x8 ah = *(const bf16x8*)(yh + kt * 32);
        bf16x8 al = *(const bf16x8*)(yl + kt * 32);
        ao0 = MFMA16(ah, bh, ao0); ao0 = MFMA16(al, bh, ao0);
      }
      {
        const float* wp = W_cls + (size_t)(colbase + lc) * NHID + (kt + 1) * 32 + kg8;
        bf16x8 bh, bl;
        split8(wp, &bh, &bl);
        bf16x8 ah = *(const bf16x8*)(yh + (kt + 1) * 32);
        bf16x8 al = *(const bf16x8*)(yl + (kt + 1) * 32);
        ao1 = MFMA16(ah, bh, ao1); ao1 = MFMA16(al, bh, ao1);
      }
    }
    float bc = b_cls[colbase + lc];
#pragma unroll
    for (int i = 0; i < 4; ++i)
      out[(size_t)(rowD + i) * NOUT + colbase + lc] = ao0[i] + ao1[i] + bc;
  }
}

extern "C" void kernel_launch(void* const* d_in, const int* in_sizes, int n_in,
                              void* d_out, int out_size, void* d_ws, size_t ws_size,
                              hipStream_t stream) {
  (void)in_sizes; (void)n_in; (void)out_size; (void)ws_size;
  const float* x     = (const float*)d_in[0];
  const float* W_inp = (const float*)d_in[1];
  const float* b_inp = (const float*)d_in[2];
  const float* W_hid = (const float*)d_in[3];
  const float* b_hid = (const float*)d_in[4];
  const float* W_z   = (const float*)d_in[5];
  const float* b_z   = (const float*)d_in[6];
  const float* W_cls = (const float*)d_in[7];
  const float* b_cls = (const float*)d_in[8];

  // workspace layout (needs ~1.54 MB): y_hi, y_lo, z_hi, z_lo, counters
  const size_t SB = (size_t)BATCH * NHID;  // 196608 elements
  unsigned short* ybh = (unsigned short*)d_ws;
  unsigned short* ybl = ybh + SB;
  unsigned short* zbh = ybl + SB;
  unsigned short* zbl = zbh + SB;
  unsigned* ctrs = (unsigned*)((char*)d_ws + 4 * SB * sizeof(unsigned short));

  // zero initial state (y0=z0=0) and barrier counters every call
  hipMemsetAsync(d_ws, 0, 4 * SB * sizeof(unsigned short) + NGRP * 128, stream);

  lem_kernel<<<dim3(NBLK), dim3(256), 0, stream>>>(
      x, W_inp, b_inp, W_hid, b_hid, W_z, b_z, W_cls, b_cls,
      (float*)d_out, ybh, ybl, zbh, zbl, ctrs);
}